// Round 12
// baseline (1077.178 us; speedup 1.0000x reference)
//
#include <hip/hip_runtime.h>
#include <math.h>

#define TWO_PI 6.283185307179586f

// HARNESS MODEL (verified R8-R11): d_out = 33,362,176 f32 = Re(out), [bc][l][m].
// Math: xr[c][k][m] = (2pi/720) * sum_n x[c][k][n] * cos(2pi n m/720)
//       out[c][l][m] = sum_k xr[c][k][m] * W[m][l][k]
// Split-bf16 MFMA (hi+lo, 3 products, f32 acc); 2-phase reg-prefetch pipeline.
// R12: restore __launch_bounds__(.,4) so prefetch state stays in VGPRs
// (R11 dropped it -> 36 VGPR -> 2GB scratch spill, s1 350->783us).

typedef __attribute__((ext_vector_type(8))) short bf16x8;
typedef __attribute__((ext_vector_type(4))) float f32x4;

__device__ inline unsigned short f2bf(float f) {
    union { float f; unsigned int u; } v; v.f = f;
    unsigned int u = v.u;
    return (unsigned short)((u + 0x7fffu + ((u >> 16) & 1u)) >> 16);  // RNE
}
__device__ inline float bf2f(unsigned short h) {
    union { unsigned int u; float f; } v; v.u = ((unsigned int)h) << 16;
    return v.f;
}
__device__ inline unsigned int packhl(float v) {
    unsigned short h = f2bf(v);
    unsigned short l = f2bf(v - bf2f(h));
    return (unsigned int)h | ((unsigned int)l << 16);
}
__device__ inline void split2(float a, float b, unsigned int& hh, unsigned int& ll) {
    unsigned short ha = f2bf(a), hb = f2bf(b);
    unsigned short la = f2bf(a - bf2f(ha)), lb = f2bf(b - bf2f(hb));
    hh = (unsigned int)ha | ((unsigned int)hb << 16);
    ll = (unsigned int)la | ((unsigned int)lb << 16);
}
// bijective chunked XCD swizzle (m204)
__device__ inline int xcd_work(int bid, int nwg) {
    int q = nwg >> 3, r = nwg & 7;
    int xcd = bid & 7, ord = bid >> 3;
    return (xcd < r ? xcd * (q + 1) : r * (q + 1) + (xcd - r) * q) + ord;
}

// ---------------- tables: EcT_hi/lo [384][736] bf16, EcT[m][n] = sigma*cos ----------------
__global__ void build_ect(unsigned short* __restrict__ Eh,
                          unsigned short* __restrict__ El) {
    const float sigma = TWO_PI / 720.0f;
    const int total = 384 * 736;
    for (int i = blockIdx.x * blockDim.x + threadIdx.x; i < total;
         i += gridDim.x * blockDim.x) {
        int m = i / 736, n = i % 736;
        float v = 0.f;
        if (m < 361 && n < 720) {
            int r = (n * m) % 720;  // exact phase reduction
            v = sigma * cosf((float)r * (TWO_PI / 720.0f));
        }
        unsigned short h = f2bf(v);
        Eh[i] = h;
        El[i] = f2bf(v - bf2f(h));
    }
}

// ---------------- stage 1: xr[m][q] = sum_n x[q][n]*EcT[m][n] ----------------
// 512 thr = 8 waves; tile 64q x 192m; 2-phase reg-prefetch pipeline
__global__ __launch_bounds__(512, 4) void s1_mfma(
    const float* __restrict__ x, const unsigned short* __restrict__ Eh,
    const unsigned short* __restrict__ El, unsigned int* __restrict__ xrp,
    const int Q) {
    __shared__ short Ah[64][40], Al[64][40];     // 5 KB each
    __shared__ short Bh[192][40], Bl[192][40];   // 15 KB each -> 40 KB

    const int work = xcd_work(blockIdx.x, gridDim.x);
    const int q0 = (work >> 1) * 64;
    const int m0g = (work & 1) * 192;
    const int t = threadIdx.x;
    const int lane = t & 63, wv = t >> 6;
    const int lr = lane & 15, lk = lane >> 4;
    const int wq = wv & 3, wm = wv >> 2;

    f32x4 acc[6];
#pragma unroll
    for (int nj = 0; nj < 6; ++nj)
#pragma unroll
        for (int r = 0; r < 4; ++r) acc[nj][r] = 0.f;

    float a_va[2], a_vb[2];
    uint4 b_v[3];

#define S1_LOADR(K0)                                                          \
    {                                                                         \
        _Pragma("unroll") for (int i = 0; i < 2; ++i) {                       \
            int id = t + i * 512;                                             \
            int r = id >> 4, kp = id & 15;                                    \
            int q = q0 + r, kg = (K0) + kp * 2;                               \
            float va = 0.f, vb = 0.f;                                         \
            if (q < Q) {                                                      \
                if (kg + 1 < 720) {                                           \
                    float2 v2 = *(const float2*)(x + (size_t)q * 720 + kg);   \
                    va = v2.x; vb = v2.y;                                     \
                } else if (kg < 720) {                                        \
                    va = x[(size_t)q * 720 + kg];                             \
                }                                                             \
            }                                                                 \
            a_va[i] = va; a_vb[i] = vb;                                       \
        }                                                                     \
        _Pragma("unroll") for (int i = 0; i < 3; ++i) {                       \
            int id = t + i * 512;                                             \
            int tab = id / 768, rid = id % 768;                               \
            int r = rid >> 2, s = rid & 3;                                    \
            const unsigned short* src =                                       \
                (tab ? El : Eh) + (size_t)(m0g + r) * 736 + (K0) + s * 8;     \
            b_v[i] = *(const uint4*)src;                                      \
        }                                                                     \
    }
#define S1_WRITES()                                                           \
    {                                                                         \
        _Pragma("unroll") for (int i = 0; i < 2; ++i) {                       \
            int id = t + i * 512;                                             \
            int r = id >> 4, kp = id & 15;                                    \
            unsigned int hh, ll;                                              \
            split2(a_va[i], a_vb[i], hh, ll);                                 \
            *(unsigned int*)&Ah[r][kp * 2] = hh;                              \
            *(unsigned int*)&Al[r][kp * 2] = ll;                              \
        }                                                                     \
        _Pragma("unroll") for (int i = 0; i < 3; ++i) {                       \
            int id = t + i * 512;                                             \
            int tab = id / 768, rid = id % 768;                               \
            int r = rid >> 2, s = rid & 3;                                    \
            if (tab) *(uint4*)&Bl[r][s * 8] = b_v[i];                         \
            else     *(uint4*)&Bh[r][s * 8] = b_v[i];                         \
        }                                                                     \
    }

    S1_LOADR(0);
    S1_WRITES();
    __syncthreads();
    for (int it = 0; it < 23; ++it) {
        if (it + 1 < 23) S1_LOADR((it + 1) * 32);   // in flight during MFMA
        bf16x8 ah = *(const bf16x8*)&Ah[wq * 16 + lr][lk * 8];
        bf16x8 al = *(const bf16x8*)&Al[wq * 16 + lr][lk * 8];
#pragma unroll
        for (int nj = 0; nj < 6; ++nj) {
            bf16x8 bh = *(const bf16x8*)&Bh[wm * 96 + nj * 16 + lr][lk * 8];
            bf16x8 bl = *(const bf16x8*)&Bl[wm * 96 + nj * 16 + lr][lk * 8];
            acc[nj] = __builtin_amdgcn_mfma_f32_16x16x32_bf16(ah, bh, acc[nj], 0, 0, 0);
            acc[nj] = __builtin_amdgcn_mfma_f32_16x16x32_bf16(ah, bl, acc[nj], 0, 0, 0);
            acc[nj] = __builtin_amdgcn_mfma_f32_16x16x32_bf16(al, bh, acc[nj], 0, 0, 0);
        }
        __syncthreads();
        if (it + 1 < 23) {
            S1_WRITES();
            __syncthreads();
        }
    }

    // epilogue: D col=m, row=q (verified mapping)
#pragma unroll
    for (int nj = 0; nj < 6; ++nj) {
        int m = m0g + wm * 96 + nj * 16 + lr;
        if (m >= 361) continue;
        size_t base = (size_t)m * Q;
#pragma unroll
        for (int reg = 0; reg < 4; ++reg) {
            int q = q0 + wq * 16 + lk * 4 + reg;
            if (q < Q) xrp[base + q] = packhl(acc[nj][reg]);
        }
    }
}

// ---------------- stage 2: per-m GEMM, tile 128bc x 64l, pipelined ----------------
// 256 thr = 4 waves (2 bc-sub x 2 l-sub); grid 361*12 flattened+swizzled
__global__ __launch_bounds__(256, 4) void s2_mfma(
    const unsigned int* __restrict__ xrp, const float* __restrict__ W,
    float* __restrict__ stg, const int CH) {
    __shared__ short Ah[128][40], Al[128][40];   // 10 KB each
    __shared__ short Bh[64][40], Bl[64][40];     // 5 KB each -> 30 KB

    const int work = xcd_work(blockIdx.x, gridDim.x);
    const int m = work / 12;
    const int rem = work % 12;
    const int half = rem / 6, lt = rem % 6;
    const int l0 = lt * 64;
    if (l0 + 63 < m) return;          // dead tile: zero-filled by transpose
    const int bcbase = half * 128;
    if (bcbase >= CH) return;
    const int Q = CH * 361;
    const int t = threadIdx.x;
    const int lane = t & 63, wv = t >> 6;
    const int lr = lane & 15, lk = lane >> 4;
    const int wbc = wv >> 1, wl = wv & 1;

    const unsigned int* Am = xrp + (size_t)m * Q;
    const float* Wm = W + (size_t)m * 130321;

    f32x4 acc[4][2];
#pragma unroll
    for (int fi = 0; fi < 4; ++fi)
#pragma unroll
        for (int ni = 0; ni < 2; ++ni)
#pragma unroll
            for (int r = 0; r < 4; ++r) acc[fi][ni][r] = 0.f;

    unsigned int pa0[8], pa1[8];
    float wva[4], wvb[4];

#define S2_LOADR(K0)                                                          \
    {                                                                         \
        _Pragma("unroll") for (int i = 0; i < 8; ++i) {                       \
            int id = t + i * 256;                                             \
            int r = id >> 4, kp = id & 15;                                    \
            int bc = bcbase + r, kg = (K0) + kp * 2;                          \
            unsigned int p0 = 0, p1 = 0;                                      \
            if (bc < CH) {                                                    \
                size_t base = (size_t)bc * 361;                               \
                if (kg < 361) p0 = Am[base + kg];                             \
                if (kg + 1 < 361) p1 = Am[base + kg + 1];                     \
            }                                                                 \
            pa0[i] = p0; pa1[i] = p1;                                         \
        }                                                                     \
        _Pragma("unroll") for (int i = 0; i < 4; ++i) {                       \
            int id = t + i * 256;                                             \
            int r = id >> 4, kp = id & 15;                                    \
            int l = l0 + r, kg = (K0) + kp * 2;                               \
            float va = 0.f, vb = 0.f;                                         \
            if (l < 361) {                                                    \
                size_t base = (size_t)l * 361;                                \
                if (kg < 361) va = Wm[base + kg];                             \
                if (kg + 1 < 361) vb = Wm[base + kg + 1];                     \
            }                                                                 \
            wva[i] = va; wvb[i] = vb;                                         \
        }                                                                     \
    }
#define S2_WRITES()                                                           \
    {                                                                         \
        _Pragma("unroll") for (int i = 0; i < 8; ++i) {                       \
            int id = t + i * 256;                                             \
            int r = id >> 4, kp = id & 15;                                    \
            *(unsigned int*)&Ah[r][kp * 2] =                                  \
                (pa0[i] & 0xffffu) | (pa1[i] << 16);                          \
            *(unsigned int*)&Al[r][kp * 2] =                                  \
                (pa0[i] >> 16) | (pa1[i] & 0xffff0000u);                      \
        }                                                                     \
        _Pragma("unroll") for (int i = 0; i < 4; ++i) {                       \
            int id = t + i * 256;                                             \
            int r = id >> 4, kp = id & 15;                                    \
            unsigned int hh, ll;                                              \
            split2(wva[i], wvb[i], hh, ll);                                   \
            *(unsigned int*)&Bh[r][kp * 2] = hh;                              \
            *(unsigned int*)&Bl[r][kp * 2] = ll;                              \
        }                                                                     \
    }

    S2_LOADR(0);
    S2_WRITES();
    __syncthreads();
    for (int it = 0; it < 12; ++it) {
        if (it + 1 < 12) S2_LOADR((it + 1) * 32);
#pragma unroll
        for (int fi = 0; fi < 4; ++fi) {
            bf16x8 ah = *(const bf16x8*)&Ah[wbc * 64 + fi * 16 + lr][lk * 8];
            bf16x8 al = *(const bf16x8*)&Al[wbc * 64 + fi * 16 + lr][lk * 8];
#pragma unroll
            for (int ni = 0; ni < 2; ++ni) {
                bf16x8 bh = *(const bf16x8*)&Bh[wl * 32 + ni * 16 + lr][lk * 8];
                bf16x8 bl = *(const bf16x8*)&Bl[wl * 32 + ni * 16 + lr][lk * 8];
                acc[fi][ni] = __builtin_amdgcn_mfma_f32_16x16x32_bf16(ah, bh, acc[fi][ni], 0, 0, 0);
                acc[fi][ni] = __builtin_amdgcn_mfma_f32_16x16x32_bf16(ah, bl, acc[fi][ni], 0, 0, 0);
                acc[fi][ni] = __builtin_amdgcn_mfma_f32_16x16x32_bf16(al, bh, acc[fi][ni], 0, 0, 0);
            }
        }
        __syncthreads();
        if (it + 1 < 12) {
            S2_WRITES();
            __syncthreads();
        }
    }

    // epilogue: stg[(m*CH+bc)*361+l]
#pragma unroll
    for (int fi = 0; fi < 4; ++fi) {
#pragma unroll
        for (int ni = 0; ni < 2; ++ni) {
            int l = l0 + wl * 32 + ni * 16 + lr;
#pragma unroll
            for (int reg = 0; reg < 4; ++reg) {
                int bc = bcbase + wbc * 64 + fi * 16 + lk * 4 + reg;
                if (bc < CH && l < 361)
                    stg[((size_t)m * CH + bc) * 361 + l] = acc[fi][ni][reg];
            }
        }
    }
}

// ---------------- transpose stg [m][q'] -> out, zero-filling dead tiles ----------------
__global__ __launch_bounds__(256) void transpose_out(const float* __restrict__ stg,
                                                     float* __restrict__ out,
                                                     const int c0, const int CH) {
    __shared__ float tile[32][33];
    const int Q = CH * 361;
    const int m0 = blockIdx.y * 32, q0 = blockIdx.x * 32;
    const int tx = threadIdx.x & 31, ty = threadIdx.x >> 5;
    for (int i = ty; i < 32; i += 8) {
        int mm = m0 + i, q = q0 + tx;
        float v = 0.f;
        if (mm < 361 && q < Q) {
            int l = q % 361;
            if ((l | 63) >= mm) v = stg[(size_t)mm * Q + q];  // live 64-tile
        }
        tile[i][tx] = v;
    }
    __syncthreads();
    for (int i = ty; i < 32; i += 8) {
        int q = q0 + i, mm = m0 + tx;
        if (mm < 361 && q < Q)
            out[((size_t)c0 * 361 + q) * 361 + mm] = tile[tx][i];
    }
}

extern "C" void kernel_launch(void* const* d_in, const int* in_sizes, int n_in,
                              void* d_out, int out_size, void* d_ws, size_t ws_size,
                              hipStream_t stream) {
    (void)out_size;
    // select inputs by element count: x = 66,539,520; W = 47,045,881
    const float* x = (const float*)d_in[0];
    const float* W = (const float*)d_in[1];
    if (n_in >= 2 && (in_sizes[0] == 47045881 || in_sizes[1] == 66539520)) {
        x = (const float*)d_in[1];
        W = (const float*)d_in[0];
    }
    float* out = (float*)d_out;

    // ws layout (bytes): EcT_hi | EcT_lo | xrp (uint, CH*130321) | stg (f32, CH*130321)
    const size_t offEh = 0;
    const size_t offEl = 565248;                 // 384*736*2
    const size_t offData = 1130496;

    const int cands[6] = {256, 128, 64, 32, 16, 8};
    int CH = 0;
    for (int i = 0; i < 6; ++i) {
        size_t need = offData + 2ull * cands[i] * 130321ull * 4ull;
        if (need <= ws_size) { CH = cands[i]; break; }
    }
    if (!CH) return;  // workspace too small: fail visibly, don't fault

    unsigned short* Eh = (unsigned short*)((char*)d_ws + offEh);
    unsigned short* El = (unsigned short*)((char*)d_ws + offEl);
    unsigned int* xrp = (unsigned int*)((char*)d_ws + offData);
    float* stg = (float*)((char*)d_ws + offData + (size_t)CH * 130321ull * 4ull);

    build_ect<<<256, 256, 0, stream>>>(Eh, El);

    const int Q = CH * 361;
    const int qt = (Q + 63) / 64;
    for (int c0 = 0; c0 < 256; c0 += CH) {
        s1_mfma<<<qt * 2, 512, 0, stream>>>(
            x + (size_t)c0 * 361 * 720, Eh, El, xrp, Q);
        s2_mfma<<<361 * 12, 256, 0, stream>>>(xrp, W, stg, CH);
        transpose_out<<<dim3((Q + 31) / 32, 12), 256, 0, stream>>>(stg, out, c0, CH);
    }
}

// Round 13
// 1062.972 us; speedup vs baseline: 1.0134x; 1.0134x over previous
//
#include <hip/hip_runtime.h>
#include <math.h>

#define TWO_PI 6.283185307179586f

// HARNESS MODEL (verified R8-R12): d_out = 33,362,176 f32 = Re(out), [bc][l][m].
// Math: xr[c][k][m] = (2pi/720) * sum_n x[c][k][n] * cos(2pi n m/720)
//       out[c][l][m] = sum_k xr[c][k][m] * W[m][l][k]
// Split-bf16 MFMA (hi+lo, 3 products, f32 acc); 2-phase reg-prefetch pipeline.
// R13: s1 rebuilt at 256 thr/block (s2's proven pipeline recipe) — at 512 thr
// the compiler spills prefetch state to scratch (R11/R12: 1.56 GB scratch writes).

typedef __attribute__((ext_vector_type(8))) short bf16x8;
typedef __attribute__((ext_vector_type(4))) float f32x4;

__device__ inline unsigned short f2bf(float f) {
    union { float f; unsigned int u; } v; v.f = f;
    unsigned int u = v.u;
    return (unsigned short)((u + 0x7fffu + ((u >> 16) & 1u)) >> 16);  // RNE
}
__device__ inline float bf2f(unsigned short h) {
    union { unsigned int u; float f; } v; v.u = ((unsigned int)h) << 16;
    return v.f;
}
__device__ inline unsigned int packhl(float v) {
    unsigned short h = f2bf(v);
    unsigned short l = f2bf(v - bf2f(h));
    return (unsigned int)h | ((unsigned int)l << 16);
}
__device__ inline void split2(float a, float b, unsigned int& hh, unsigned int& ll) {
    unsigned short ha = f2bf(a), hb = f2bf(b);
    unsigned short la = f2bf(a - bf2f(ha)), lb = f2bf(b - bf2f(hb));
    hh = (unsigned int)ha | ((unsigned int)hb << 16);
    ll = (unsigned int)la | ((unsigned int)lb << 16);
}
// bijective chunked XCD swizzle (m204)
__device__ inline int xcd_work(int bid, int nwg) {
    int q = nwg >> 3, r = nwg & 7;
    int xcd = bid & 7, ord = bid >> 3;
    return (xcd < r ? xcd * (q + 1) : r * (q + 1) + (xcd - r) * q) + ord;
}

// ---------------- tables: EcT_hi/lo [384][736] bf16, EcT[m][n] = sigma*cos ----------------
__global__ void build_ect(unsigned short* __restrict__ Eh,
                          unsigned short* __restrict__ El) {
    const float sigma = TWO_PI / 720.0f;
    const int total = 384 * 736;
    for (int i = blockIdx.x * blockDim.x + threadIdx.x; i < total;
         i += gridDim.x * blockDim.x) {
        int m = i / 736, n = i % 736;
        float v = 0.f;
        if (m < 361 && n < 720) {
            int r = (n * m) % 720;  // exact phase reduction
            v = sigma * cosf((float)r * (TWO_PI / 720.0f));
        }
        unsigned short h = f2bf(v);
        Eh[i] = h;
        El[i] = f2bf(v - bf2f(h));
    }
}

// ---------------- stage 1: xr[m][q] = sum_n x[q][n]*EcT[m][n] ----------------
// 256 thr = 4 waves; tile 64q x 96m; 2-phase reg-prefetch (s2's proven recipe)
// work decode: q0 = (work>>2)*64, mt = work&3 (4 m-tiles of 96) -> mt inner
// so the 4 blocks sharing a q-panel land on one XCD (x fetched once).
__global__ __launch_bounds__(256, 4) void s1_mfma(
    const float* __restrict__ x, const unsigned short* __restrict__ Eh,
    const unsigned short* __restrict__ El, unsigned int* __restrict__ xrp,
    const int Q) {
    __shared__ short Ah[64][40], Al[64][40];     // 5 KB each
    __shared__ short Bh[96][40], Bl[96][40];     // 7.5 KB each -> 25 KB

    const int work = xcd_work(blockIdx.x, gridDim.x);
    const int q0 = (work >> 2) * 64;
    const int m0g = (work & 3) * 96;
    const int t = threadIdx.x;
    const int lane = t & 63, wv = t >> 6;
    const int lr = lane & 15, lk = lane >> 4;
    const int wq = wv;   // wave = one 16-row q fragment

    f32x4 acc[6];
#pragma unroll
    for (int nj = 0; nj < 6; ++nj)
#pragma unroll
        for (int r = 0; r < 4; ++r) acc[nj][r] = 0.f;

    float a_va[4], a_vb[4];
    uint4 b_v[3];

#define S1_LOADR(K0)                                                          \
    {                                                                         \
        _Pragma("unroll") for (int i = 0; i < 4; ++i) {                       \
            int id = t + i * 256;                                             \
            int r = id >> 4, kp = id & 15;                                    \
            int q = q0 + r, kg = (K0) + kp * 2;                               \
            float va = 0.f, vb = 0.f;                                         \
            if (q < Q) {                                                      \
                if (kg + 1 < 720) {                                           \
                    float2 v2 = *(const float2*)(x + (size_t)q * 720 + kg);   \
                    va = v2.x; vb = v2.y;                                     \
                } else if (kg < 720) {                                        \
                    va = x[(size_t)q * 720 + kg];                             \
                }                                                             \
            }                                                                 \
            a_va[i] = va; a_vb[i] = vb;                                       \
        }                                                                     \
        _Pragma("unroll") for (int i = 0; i < 3; ++i) {                       \
            int id = t + i * 256;                                             \
            int tab = id / 384, rid = id % 384;                               \
            int r = rid >> 2, s = rid & 3;                                    \
            const unsigned short* src =                                       \
                (tab ? El : Eh) + (size_t)(m0g + r) * 736 + (K0) + s * 8;     \
            b_v[i] = *(const uint4*)src;                                      \
        }                                                                     \
    }
#define S1_WRITES()                                                           \
    {                                                                         \
        _Pragma("unroll") for (int i = 0; i < 4; ++i) {                       \
            int id = t + i * 256;                                             \
            int r = id >> 4, kp = id & 15;                                    \
            unsigned int hh, ll;                                              \
            split2(a_va[i], a_vb[i], hh, ll);                                 \
            *(unsigned int*)&Ah[r][kp * 2] = hh;                              \
            *(unsigned int*)&Al[r][kp * 2] = ll;                              \
        }                                                                     \
        _Pragma("unroll") for (int i = 0; i < 3; ++i) {                       \
            int id = t + i * 256;                                             \
            int tab = id / 384, rid = id % 384;                               \
            int r = rid >> 2, s = rid & 3;                                    \
            if (tab) *(uint4*)&Bl[r][s * 8] = b_v[i];                         \
            else     *(uint4*)&Bh[r][s * 8] = b_v[i];                         \
        }                                                                     \
    }

    S1_LOADR(0);
    S1_WRITES();
    __syncthreads();
    for (int it = 0; it < 23; ++it) {
        if (it + 1 < 23) S1_LOADR((it + 1) * 32);   // in flight during MFMA
        bf16x8 ah = *(const bf16x8*)&Ah[wq * 16 + lr][lk * 8];
        bf16x8 al = *(const bf16x8*)&Al[wq * 16 + lr][lk * 8];
#pragma unroll
        for (int nj = 0; nj < 6; ++nj) {
            bf16x8 bh = *(const bf16x8*)&Bh[nj * 16 + lr][lk * 8];
            bf16x8 bl = *(const bf16x8*)&Bl[nj * 16 + lr][lk * 8];
            acc[nj] = __builtin_amdgcn_mfma_f32_16x16x32_bf16(ah, bh, acc[nj], 0, 0, 0);
            acc[nj] = __builtin_amdgcn_mfma_f32_16x16x32_bf16(ah, bl, acc[nj], 0, 0, 0);
            acc[nj] = __builtin_amdgcn_mfma_f32_16x16x32_bf16(al, bh, acc[nj], 0, 0, 0);
        }
        __syncthreads();
        if (it + 1 < 23) {
            S1_WRITES();
            __syncthreads();
        }
    }

    // epilogue: D col=m, row=q (verified mapping)
#pragma unroll
    for (int nj = 0; nj < 6; ++nj) {
        int m = m0g + nj * 16 + lr;
        if (m >= 361) continue;
        size_t base = (size_t)m * Q;
#pragma unroll
        for (int reg = 0; reg < 4; ++reg) {
            int q = q0 + wq * 16 + lk * 4 + reg;
            if (q < Q) xrp[base + q] = packhl(acc[nj][reg]);
        }
    }
}

// ---------------- stage 2: per-m GEMM, tile 128bc x 64l, pipelined ----------------
// 256 thr = 4 waves (2 bc-sub x 2 l-sub); grid 361*12 flattened+swizzled
__global__ __launch_bounds__(256, 4) void s2_mfma(
    const unsigned int* __restrict__ xrp, const float* __restrict__ W,
    float* __restrict__ stg, const int CH) {
    __shared__ short Ah[128][40], Al[128][40];   // 10 KB each
    __shared__ short Bh[64][40], Bl[64][40];     // 5 KB each -> 30 KB

    const int work = xcd_work(blockIdx.x, gridDim.x);
    const int m = work / 12;
    const int rem = work % 12;
    const int half = rem / 6, lt = rem % 6;
    const int l0 = lt * 64;
    if (l0 + 63 < m) return;          // dead tile: zero-filled by transpose
    const int bcbase = half * 128;
    if (bcbase >= CH) return;
    const int Q = CH * 361;
    const int t = threadIdx.x;
    const int lane = t & 63, wv = t >> 6;
    const int lr = lane & 15, lk = lane >> 4;
    const int wbc = wv >> 1, wl = wv & 1;

    const unsigned int* Am = xrp + (size_t)m * Q;
    const float* Wm = W + (size_t)m * 130321;

    f32x4 acc[4][2];
#pragma unroll
    for (int fi = 0; fi < 4; ++fi)
#pragma unroll
        for (int ni = 0; ni < 2; ++ni)
#pragma unroll
            for (int r = 0; r < 4; ++r) acc[fi][ni][r] = 0.f;

    unsigned int pa0[8], pa1[8];
    float wva[4], wvb[4];

#define S2_LOADR(K0)                                                          \
    {                                                                         \
        _Pragma("unroll") for (int i = 0; i < 8; ++i) {                       \
            int id = t + i * 256;                                             \
            int r = id >> 4, kp = id & 15;                                    \
            int bc = bcbase + r, kg = (K0) + kp * 2;                          \
            unsigned int p0 = 0, p1 = 0;                                      \
            if (bc < CH) {                                                    \
                size_t base = (size_t)bc * 361;                               \
                if (kg < 361) p0 = Am[base + kg];                             \
                if (kg + 1 < 361) p1 = Am[base + kg + 1];                     \
            }                                                                 \
            pa0[i] = p0; pa1[i] = p1;                                         \
        }                                                                     \
        _Pragma("unroll") for (int i = 0; i < 4; ++i) {                       \
            int id = t + i * 256;                                             \
            int r = id >> 4, kp = id & 15;                                    \
            int l = l0 + r, kg = (K0) + kp * 2;                               \
            float va = 0.f, vb = 0.f;                                         \
            if (l < 361) {                                                    \
                size_t base = (size_t)l * 361;                                \
                if (kg < 361) va = Wm[base + kg];                             \
                if (kg + 1 < 361) vb = Wm[base + kg + 1];                     \
            }                                                                 \
            wva[i] = va; wvb[i] = vb;                                         \
        }                                                                     \
    }
#define S2_WRITES()                                                           \
    {                                                                         \
        _Pragma("unroll") for (int i = 0; i < 8; ++i) {                       \
            int id = t + i * 256;                                             \
            int r = id >> 4, kp = id & 15;                                    \
            *(unsigned int*)&Ah[r][kp * 2] =                                  \
                (pa0[i] & 0xffffu) | (pa1[i] << 16);                          \
            *(unsigned int*)&Al[r][kp * 2] =                                  \
                (pa0[i] >> 16) | (pa1[i] & 0xffff0000u);                      \
        }                                                                     \
        _Pragma("unroll") for (int i = 0; i < 4; ++i) {                       \
            int id = t + i * 256;                                             \
            int r = id >> 4, kp = id & 15;                                    \
            unsigned int hh, ll;                                              \
            split2(wva[i], wvb[i], hh, ll);                                   \
            *(unsigned int*)&Bh[r][kp * 2] = hh;                              \
            *(unsigned int*)&Bl[r][kp * 2] = ll;                              \
        }                                                                     \
    }

    S2_LOADR(0);
    S2_WRITES();
    __syncthreads();
    for (int it = 0; it < 12; ++it) {
        if (it + 1 < 12) S2_LOADR((it + 1) * 32);
#pragma unroll
        for (int fi = 0; fi < 4; ++fi) {
            bf16x8 ah = *(const bf16x8*)&Ah[wbc * 64 + fi * 16 + lr][lk * 8];
            bf16x8 al = *(const bf16x8*)&Al[wbc * 64 + fi * 16 + lr][lk * 8];
#pragma unroll
            for (int ni = 0; ni < 2; ++ni) {
                bf16x8 bh = *(const bf16x8*)&Bh[wl * 32 + ni * 16 + lr][lk * 8];
                bf16x8 bl = *(const bf16x8*)&Bl[wl * 32 + ni * 16 + lr][lk * 8];
                acc[fi][ni] = __builtin_amdgcn_mfma_f32_16x16x32_bf16(ah, bh, acc[fi][ni], 0, 0, 0);
                acc[fi][ni] = __builtin_amdgcn_mfma_f32_16x16x32_bf16(ah, bl, acc[fi][ni], 0, 0, 0);
                acc[fi][ni] = __builtin_amdgcn_mfma_f32_16x16x32_bf16(al, bh, acc[fi][ni], 0, 0, 0);
            }
        }
        __syncthreads();
        if (it + 1 < 12) {
            S2_WRITES();
            __syncthreads();
        }
    }

    // epilogue: stg[(m*CH+bc)*361+l]
#pragma unroll
    for (int fi = 0; fi < 4; ++fi) {
#pragma unroll
        for (int ni = 0; ni < 2; ++ni) {
            int l = l0 + wl * 32 + ni * 16 + lr;
#pragma unroll
            for (int reg = 0; reg < 4; ++reg) {
                int bc = bcbase + wbc * 64 + fi * 16 + lk * 4 + reg;
                if (bc < CH && l < 361)
                    stg[((size_t)m * CH + bc) * 361 + l] = acc[fi][ni][reg];
            }
        }
    }
}

// ---------------- transpose stg [m][q'] -> out, zero-filling dead tiles ----------------
__global__ __launch_bounds__(256) void transpose_out(const float* __restrict__ stg,
                                                     float* __restrict__ out,
                                                     const int c0, const int CH) {
    __shared__ float tile[32][33];
    const int Q = CH * 361;
    const int m0 = blockIdx.y * 32, q0 = blockIdx.x * 32;
    const int tx = threadIdx.x & 31, ty = threadIdx.x >> 5;
    for (int i = ty; i < 32; i += 8) {
        int mm = m0 + i, q = q0 + tx;
        float v = 0.f;
        if (mm < 361 && q < Q) {
            int l = q % 361;
            if ((l | 63) >= mm) v = stg[(size_t)mm * Q + q];  // live 64-tile
        }
        tile[i][tx] = v;
    }
    __syncthreads();
    for (int i = ty; i < 32; i += 8) {
        int q = q0 + i, mm = m0 + tx;
        if (mm < 361 && q < Q)
            out[((size_t)c0 * 361 + q) * 361 + mm] = tile[tx][i];
    }
}

extern "C" void kernel_launch(void* const* d_in, const int* in_sizes, int n_in,
                              void* d_out, int out_size, void* d_ws, size_t ws_size,
                              hipStream_t stream) {
    (void)out_size;
    // select inputs by element count: x = 66,539,520; W = 47,045,881
    const float* x = (const float*)d_in[0];
    const float* W = (const float*)d_in[1];
    if (n_in >= 2 && (in_sizes[0] == 47045881 || in_sizes[1] == 66539520)) {
        x = (const float*)d_in[1];
        W = (const float*)d_in[0];
    }
    float* out = (float*)d_out;

    // ws layout (bytes): EcT_hi | EcT_lo | xrp (uint, CH*130321) | stg (f32, CH*130321)
    const size_t offEh = 0;
    const size_t offEl = 565248;                 // 384*736*2
    const size_t offData = 1130496;

    const int cands[6] = {256, 128, 64, 32, 16, 8};
    int CH = 0;
    for (int i = 0; i < 6; ++i) {
        size_t need = offData + 2ull * cands[i] * 130321ull * 4ull;
        if (need <= ws_size) { CH = cands[i]; break; }
    }
    if (!CH) return;  // workspace too small: fail visibly, don't fault

    unsigned short* Eh = (unsigned short*)((char*)d_ws + offEh);
    unsigned short* El = (unsigned short*)((char*)d_ws + offEl);
    unsigned int* xrp = (unsigned int*)((char*)d_ws + offData);
    float* stg = (float*)((char*)d_ws + offData + (size_t)CH * 130321ull * 4ull);

    build_ect<<<256, 256, 0, stream>>>(Eh, El);

    const int Q = CH * 361;
    const int qt = (Q + 63) / 64;
    for (int c0 = 0; c0 < 256; c0 += CH) {
        s1_mfma<<<qt * 4, 256, 0, stream>>>(
            x + (size_t)c0 * 361 * 720, Eh, El, xrp, Q);
        s2_mfma<<<361 * 12, 256, 0, stream>>>(xrp, W, stg, CH);
        transpose_out<<<dim3((Q + 31) / 32, 12), 256, 0, stream>>>(stg, out, c0, CH);
    }
}

// Round 14
// 645.424 us; speedup vs baseline: 1.6689x; 1.6469x over previous
//
#include <hip/hip_runtime.h>
#include <math.h>

#define TWO_PI 6.283185307179586f

// HARNESS MODEL (verified R8-R13): d_out = 33,362,176 f32 = Re(out), [bc][l][m].
// Math: xr[c][k][m] = (2pi/720) * sum_n x[c][k][n] * cos(2pi n m/720)
//       out[c][l][m] = sum_k xr[c][k][m] * W[m][l][k]
// Split-bf16 MFMA (hi+lo, 3 products, f32 acc).
// R14: s1 prefetches ONLY A (scalar floats, s2's proven no-spill pattern);
// B (cosine table, L2-resident) is loaded synchronously in the LDS-write
// phase. R13's uint4 b_v[3] held across the barrier spilled ~1.4 GB scratch.

typedef __attribute__((ext_vector_type(8))) short bf16x8;
typedef __attribute__((ext_vector_type(4))) float f32x4;

__device__ inline unsigned short f2bf(float f) {
    union { float f; unsigned int u; } v; v.f = f;
    unsigned int u = v.u;
    return (unsigned short)((u + 0x7fffu + ((u >> 16) & 1u)) >> 16);  // RNE
}
__device__ inline float bf2f(unsigned short h) {
    union { unsigned int u; float f; } v; v.u = ((unsigned int)h) << 16;
    return v.f;
}
__device__ inline unsigned int packhl(float v) {
    unsigned short h = f2bf(v);
    unsigned short l = f2bf(v - bf2f(h));
    return (unsigned int)h | ((unsigned int)l << 16);
}
__device__ inline void split2(float a, float b, unsigned int& hh, unsigned int& ll) {
    unsigned short ha = f2bf(a), hb = f2bf(b);
    unsigned short la = f2bf(a - bf2f(ha)), lb = f2bf(b - bf2f(hb));
    hh = (unsigned int)ha | ((unsigned int)hb << 16);
    ll = (unsigned int)la | ((unsigned int)lb << 16);
}
// bijective chunked XCD swizzle (m204)
__device__ inline int xcd_work(int bid, int nwg) {
    int q = nwg >> 3, r = nwg & 7;
    int xcd = bid & 7, ord = bid >> 3;
    return (xcd < r ? xcd * (q + 1) : r * (q + 1) + (xcd - r) * q) + ord;
}

// ---------------- tables: EcT_hi/lo [384][736] bf16, EcT[m][n] = sigma*cos ----------------
__global__ void build_ect(unsigned short* __restrict__ Eh,
                          unsigned short* __restrict__ El) {
    const float sigma = TWO_PI / 720.0f;
    const int total = 384 * 736;
    for (int i = blockIdx.x * blockDim.x + threadIdx.x; i < total;
         i += gridDim.x * blockDim.x) {
        int m = i / 736, n = i % 736;
        float v = 0.f;
        if (m < 361 && n < 720) {
            int r = (n * m) % 720;  // exact phase reduction
            v = sigma * cosf((float)r * (TWO_PI / 720.0f));
        }
        unsigned short h = f2bf(v);
        Eh[i] = h;
        El[i] = f2bf(v - bf2f(h));
    }
}

// ---------------- stage 1: xr[m][q] = sum_n x[q][n]*EcT[m][n] ----------------
// 256 thr = 4 waves; tile 64q x 96m; A reg-prefetched (scalars), B direct L2->LDS
__global__ __launch_bounds__(256, 4) void s1_mfma(
    const float* __restrict__ x, const unsigned short* __restrict__ Eh,
    const unsigned short* __restrict__ El, unsigned int* __restrict__ xrp,
    const int Q) {
    __shared__ short Ah[64][40], Al[64][40];     // 5 KB each
    __shared__ short Bh[96][40], Bl[96][40];     // 7.5 KB each -> 25 KB

    const int work = xcd_work(blockIdx.x, gridDim.x);
    const int q0 = (work >> 2) * 64;
    const int m0g = (work & 3) * 96;
    const int t = threadIdx.x;
    const int lane = t & 63, wv = t >> 6;
    const int lr = lane & 15, lk = lane >> 4;
    const int wq = wv;   // wave = one 16-row q fragment

    f32x4 acc[6];
#pragma unroll
    for (int nj = 0; nj < 6; ++nj)
#pragma unroll
        for (int r = 0; r < 4; ++r) acc[nj][r] = 0.f;

    float a_va[4], a_vb[4];   // scalar cross-barrier prefetch (no-spill pattern)

#define S1_LOADA(K0)                                                          \
    {                                                                         \
        _Pragma("unroll") for (int i = 0; i < 4; ++i) {                       \
            int id = t + i * 256;                                             \
            int r = id >> 4, kp = id & 15;                                    \
            int q = q0 + r, kg = (K0) + kp * 2;                               \
            float va = 0.f, vb = 0.f;                                         \
            if (q < Q) {                                                      \
                if (kg + 1 < 720) {                                           \
                    float2 v2 = *(const float2*)(x + (size_t)q * 720 + kg);   \
                    va = v2.x; vb = v2.y;                                     \
                } else if (kg < 720) {                                        \
                    va = x[(size_t)q * 720 + kg];                             \
                }                                                             \
            }                                                                 \
            a_va[i] = va; a_vb[i] = vb;                                       \
        }                                                                     \
    }
    // write A from regs; load B from L2 and write LDS (no cross-barrier regs)
#define S1_WRITES(K0)                                                         \
    {                                                                         \
        _Pragma("unroll") for (int i = 0; i < 4; ++i) {                       \
            int id = t + i * 256;                                             \
            int r = id >> 4, kp = id & 15;                                    \
            unsigned int hh, ll;                                              \
            split2(a_va[i], a_vb[i], hh, ll);                                 \
            *(unsigned int*)&Ah[r][kp * 2] = hh;                              \
            *(unsigned int*)&Al[r][kp * 2] = ll;                              \
        }                                                                     \
        _Pragma("unroll") for (int i = 0; i < 3; ++i) {                       \
            int id = t + i * 256;                                             \
            int tab = id / 384, rid = id % 384;                               \
            int r = rid >> 2, s = rid & 3;                                    \
            const unsigned short* src =                                       \
                (tab ? El : Eh) + (size_t)(m0g + r) * 736 + (K0) + s * 8;     \
            uint4 v = *(const uint4*)src;                                     \
            if (tab) *(uint4*)&Bl[r][s * 8] = v;                              \
            else     *(uint4*)&Bh[r][s * 8] = v;                              \
        }                                                                     \
    }

    S1_LOADA(0);
    S1_WRITES(0);
    __syncthreads();
    for (int it = 0; it < 23; ++it) {
        if (it + 1 < 23) S1_LOADA((it + 1) * 32);   // x HBM latency hidden here
        bf16x8 ah = *(const bf16x8*)&Ah[wq * 16 + lr][lk * 8];
        bf16x8 al = *(const bf16x8*)&Al[wq * 16 + lr][lk * 8];
#pragma unroll
        for (int nj = 0; nj < 6; ++nj) {
            bf16x8 bh = *(const bf16x8*)&Bh[nj * 16 + lr][lk * 8];
            bf16x8 bl = *(const bf16x8*)&Bl[nj * 16 + lr][lk * 8];
            acc[nj] = __builtin_amdgcn_mfma_f32_16x16x32_bf16(ah, bh, acc[nj], 0, 0, 0);
            acc[nj] = __builtin_amdgcn_mfma_f32_16x16x32_bf16(ah, bl, acc[nj], 0, 0, 0);
            acc[nj] = __builtin_amdgcn_mfma_f32_16x16x32_bf16(al, bh, acc[nj], 0, 0, 0);
        }
        __syncthreads();
        if (it + 1 < 23) {
            S1_WRITES((it + 1) * 32);
            __syncthreads();
        }
    }

    // epilogue: D col=m, row=q (verified mapping)
#pragma unroll
    for (int nj = 0; nj < 6; ++nj) {
        int m = m0g + nj * 16 + lr;
        if (m >= 361) continue;
        size_t base = (size_t)m * Q;
#pragma unroll
        for (int reg = 0; reg < 4; ++reg) {
            int q = q0 + wq * 16 + lk * 4 + reg;
            if (q < Q) xrp[base + q] = packhl(acc[nj][reg]);
        }
    }
}

// ---------------- stage 2: per-m GEMM, tile 128bc x 64l, pipelined ----------------
// 256 thr = 4 waves (2 bc-sub x 2 l-sub); grid 361*12 flattened+swizzled
__global__ __launch_bounds__(256, 4) void s2_mfma(
    const unsigned int* __restrict__ xrp, const float* __restrict__ W,
    float* __restrict__ stg, const int CH) {
    __shared__ short Ah[128][40], Al[128][40];   // 10 KB each
    __shared__ short Bh[64][40], Bl[64][40];     // 5 KB each -> 30 KB

    const int work = xcd_work(blockIdx.x, gridDim.x);
    const int m = work / 12;
    const int rem = work % 12;
    const int half = rem / 6, lt = rem % 6;
    const int l0 = lt * 64;
    if (l0 + 63 < m) return;          // dead tile: zero-filled by transpose
    const int bcbase = half * 128;
    if (bcbase >= CH) return;
    const int Q = CH * 361;
    const int t = threadIdx.x;
    const int lane = t & 63, wv = t >> 6;
    const int lr = lane & 15, lk = lane >> 4;
    const int wbc = wv >> 1, wl = wv & 1;

    const unsigned int* Am = xrp + (size_t)m * Q;
    const float* Wm = W + (size_t)m * 130321;

    f32x4 acc[4][2];
#pragma unroll
    for (int fi = 0; fi < 4; ++fi)
#pragma unroll
        for (int ni = 0; ni < 2; ++ni)
#pragma unroll
            for (int r = 0; r < 4; ++r) acc[fi][ni][r] = 0.f;

    unsigned int pa0[8], pa1[8];
    float wva[4], wvb[4];

#define S2_LOADR(K0)                                                          \
    {                                                                         \
        _Pragma("unroll") for (int i = 0; i < 8; ++i) {                       \
            int id = t + i * 256;                                             \
            int r = id >> 4, kp = id & 15;                                    \
            int bc = bcbase + r, kg = (K0) + kp * 2;                          \
            unsigned int p0 = 0, p1 = 0;                                      \
            if (bc < CH) {                                                    \
                size_t base = (size_t)bc * 361;                               \
                if (kg < 361) p0 = Am[base + kg];                             \
                if (kg + 1 < 361) p1 = Am[base + kg + 1];                     \
            }                                                                 \
            pa0[i] = p0; pa1[i] = p1;                                         \
        }                                                                     \
        _Pragma("unroll") for (int i = 0; i < 4; ++i) {                       \
            int id = t + i * 256;                                             \
            int r = id >> 4, kp = id & 15;                                    \
            int l = l0 + r, kg = (K0) + kp * 2;                               \
            float va = 0.f, vb = 0.f;                                         \
            if (l < 361) {                                                    \
                size_t base = (size_t)l * 361;                                \
                if (kg < 361) va = Wm[base + kg];                             \
                if (kg + 1 < 361) vb = Wm[base + kg + 1];                     \
            }                                                                 \
            wva[i] = va; wvb[i] = vb;                                         \
        }                                                                     \
    }
#define S2_WRITES()                                                           \
    {                                                                         \
        _Pragma("unroll") for (int i = 0; i < 8; ++i) {                       \
            int id = t + i * 256;                                             \
            int r = id >> 4, kp = id & 15;                                    \
            *(unsigned int*)&Ah[r][kp * 2] =                                  \
                (pa0[i] & 0xffffu) | (pa1[i] << 16);                          \
            *(unsigned int*)&Al[r][kp * 2] =                                  \
                (pa0[i] >> 16) | (pa1[i] & 0xffff0000u);                      \
        }                                                                     \
        _Pragma("unroll") for (int i = 0; i < 4; ++i) {                       \
            int id = t + i * 256;                                             \
            int r = id >> 4, kp = id & 15;                                    \
            unsigned int hh, ll;                                              \
            split2(wva[i], wvb[i], hh, ll);                                   \
            *(unsigned int*)&Bh[r][kp * 2] = hh;                              \
            *(unsigned int*)&Bl[r][kp * 2] = ll;                              \
        }                                                                     \
    }

    S2_LOADR(0);
    S2_WRITES();
    __syncthreads();
    for (int it = 0; it < 12; ++it) {
        if (it + 1 < 12) S2_LOADR((it + 1) * 32);
#pragma unroll
        for (int fi = 0; fi < 4; ++fi) {
            bf16x8 ah = *(const bf16x8*)&Ah[wbc * 64 + fi * 16 + lr][lk * 8];
            bf16x8 al = *(const bf16x8*)&Al[wbc * 64 + fi * 16 + lr][lk * 8];
#pragma unroll
            for (int ni = 0; ni < 2; ++ni) {
                bf16x8 bh = *(const bf16x8*)&Bh[wl * 32 + ni * 16 + lr][lk * 8];
                bf16x8 bl = *(const bf16x8*)&Bl[wl * 32 + ni * 16 + lr][lk * 8];
                acc[fi][ni] = __builtin_amdgcn_mfma_f32_16x16x32_bf16(ah, bh, acc[fi][ni], 0, 0, 0);
                acc[fi][ni] = __builtin_amdgcn_mfma_f32_16x16x32_bf16(ah, bl, acc[fi][ni], 0, 0, 0);
                acc[fi][ni] = __builtin_amdgcn_mfma_f32_16x16x32_bf16(al, bh, acc[fi][ni], 0, 0, 0);
            }
        }
        __syncthreads();
        if (it + 1 < 12) {
            S2_WRITES();
            __syncthreads();
        }
    }

    // epilogue: stg[(m*CH+bc)*361+l]
#pragma unroll
    for (int fi = 0; fi < 4; ++fi) {
#pragma unroll
        for (int ni = 0; ni < 2; ++ni) {
            int l = l0 + wl * 32 + ni * 16 + lr;
#pragma unroll
            for (int reg = 0; reg < 4; ++reg) {
                int bc = bcbase + wbc * 64 + fi * 16 + lk * 4 + reg;
                if (bc < CH && l < 361)
                    stg[((size_t)m * CH + bc) * 361 + l] = acc[fi][ni][reg];
            }
        }
    }
}

// ---------------- transpose stg [m][q'] -> out, zero-filling dead tiles ----------------
__global__ __launch_bounds__(256) void transpose_out(const float* __restrict__ stg,
                                                     float* __restrict__ out,
                                                     const int c0, const int CH) {
    __shared__ float tile[32][33];
    const int Q = CH * 361;
    const int m0 = blockIdx.y * 32, q0 = blockIdx.x * 32;
    const int tx = threadIdx.x & 31, ty = threadIdx.x >> 5;
    for (int i = ty; i < 32; i += 8) {
        int mm = m0 + i, q = q0 + tx;
        float v = 0.f;
        if (mm < 361 && q < Q) {
            int l = q % 361;
            if ((l | 63) >= mm) v = stg[(size_t)mm * Q + q];  // live 64-tile
        }
        tile[i][tx] = v;
    }
    __syncthreads();
    for (int i = ty; i < 32; i += 8) {
        int q = q0 + i, mm = m0 + tx;
        if (mm < 361 && q < Q)
            out[((size_t)c0 * 361 + q) * 361 + mm] = tile[tx][i];
    }
}

extern "C" void kernel_launch(void* const* d_in, const int* in_sizes, int n_in,
                              void* d_out, int out_size, void* d_ws, size_t ws_size,
                              hipStream_t stream) {
    (void)out_size;
    // select inputs by element count: x = 66,539,520; W = 47,045,881
    const float* x = (const float*)d_in[0];
    const float* W = (const float*)d_in[1];
    if (n_in >= 2 && (in_sizes[0] == 47045881 || in_sizes[1] == 66539520)) {
        x = (const float*)d_in[1];
        W = (const float*)d_in[0];
    }
    float* out = (float*)d_out;

    // ws layout (bytes): EcT_hi | EcT_lo | xrp (uint, CH*130321) | stg (f32, CH*130321)
    const size_t offEh = 0;
    const size_t offEl = 565248;                 // 384*736*2
    const size_t offData = 1130496;

    const int cands[6] = {256, 128, 64, 32, 16, 8};
    int CH = 0;
    for (int i = 0; i < 6; ++i) {
        size_t need = offData + 2ull * cands[i] * 130321ull * 4ull;
        if (need <= ws_size) { CH = cands[i]; break; }
    }
    if (!CH) return;  // workspace too small: fail visibly, don't fault

    unsigned short* Eh = (unsigned short*)((char*)d_ws + offEh);
    unsigned short* El = (unsigned short*)((char*)d_ws + offEl);
    unsigned int* xrp = (unsigned int*)((char*)d_ws + offData);
    float* stg = (float*)((char*)d_ws + offData + (size_t)CH * 130321ull * 4ull);

    build_ect<<<256, 256, 0, stream>>>(Eh, El);

    const int Q = CH * 361;
    const int qt = (Q + 63) / 64;
    for (int c0 = 0; c0 < 256; c0 += CH) {
        s1_mfma<<<qt * 4, 256, 0, stream>>>(
            x + (size_t)c0 * 361 * 720, Eh, El, xrp, Q);
        s2_mfma<<<361 * 12, 256, 0, stream>>>(xrp, W, stg, CH);
        transpose_out<<<dim3((Q + 31) / 32, 12), 256, 0, stream>>>(stg, out, c0, CH);
    }
}